// Round 10
// baseline (280.793 us; speedup 1.0000x reference)
//
#include <hip/hip_runtime.h>
#include <stdint.h>

#define NB 4
#define NPTS 4096
#define MPTS 16384
#define CIN 256
#define CH0 512
#define CH1 512
#define CH2 256
#define ROWS (NB * MPTS)          // 65536
#define POS_OUT_OFF (ROWS * CH2)               // 16777216
#define BATCH_OUT_OFF (POS_OUT_OFF + ROWS * 3) // 16973824
#define CELL_CAP 40               // lambda=8/cell
#define QCAP 96                   // lambda=32/cell

using u16 = unsigned short;
using u32 = unsigned int;
using u64 = unsigned long long;

typedef __bf16 bf16x8 __attribute__((ext_vector_type(8)));
typedef float f32x4 __attribute__((ext_vector_type(4)));

__device__ __forceinline__ u16 f2bf(float f) {
  u32 u = __builtin_bit_cast(u32, f);
  u32 r = u + 0x7fffu + ((u >> 16) & 1u);   // round-to-nearest-even
  return (u16)(r >> 16);
}

__device__ __forceinline__ u32 flipf(float f) {
  u32 u = __builtin_bit_cast(u32, f);
  return u ^ ((u32)((int)u >> 31) | 0x80000000u);
}
__device__ __forceinline__ float unflipf(u32 f) {
  u32 m = (~(u32)((int)f >> 31)) | 0x80000000u;
  return __builtin_bit_cast(float, f ^ m);
}

__device__ __forceinline__ void ins3(u64 v, u64& k0, u64& k1, u64& k2) {
  u64 a = k0 < v ? v : k0;
  k0 = k0 < v ? k0 : v;
  u64 bb = k1 < a ? a : k1;
  k1 = k1 < a ? k1 : a;
  k2 = k2 < bb ? k2 : bb;
}

__device__ __forceinline__ void merge3(u64 r0, u64 r1, u64 r2,
                                       u64& k0, u64& k1, u64& k2) {
  u64 t = k0 < r0 ? r0 : k0;
  k0 = k0 < r0 ? k0 : r0;
  u64 u = k1 < r1 ? k1 : r1;
  u64 mtu = t < u ? u : t;
  k1 = t < u ? t : u;
  u64 v = k2 < r2 ? k2 : r2;
  k2 = mtu < v ? mtu : v;
}

__device__ __forceinline__ u64 shfl_xor_u64_w8(u64 v, int mask) {
  u32 lo = (u32)v, hi = (u32)(v >> 32);
  lo = (u32)__shfl_xor((int)lo, mask, 8);
  hi = (u32)__shfl_xor((int)hi, mask, 8);
  return ((u64)hi << 32) | lo;
}

// ---------------------------------------------------------------- W pack
// (unchanged from R9 — operand-role swap uses the same lane layout)
__global__ __launch_bounds__(256) void prep_kernel(
    const float* __restrict__ W1, const float* __restrict__ W2,
    u16* __restrict__ W1s, u16* __restrict__ W2s) {
  const int t = blockIdx.x * 256 + threadIdx.x;   // 192 blocks -> 49152
  if (t < 32768) {
    const int l = t & 63, ni = (t >> 6) & 3, wd = (t >> 8) & 7, kt = t >> 11;
    const int fr = l & 15, g = l >> 4;
    const int n = wd * 64 + ni * 16 + fr;
    u16 o[8];
#pragma unroll
    for (int j = 0; j < 8; ++j)
      o[j] = f2bf(W1[(kt * 32 + g * 8 + j) * CH1 + n]);
    *(uint4*)(W1s + (size_t)t * 8) = *(const uint4*)o;
  } else {
    const int c = t - 32768;                      // 0..16383
    const int l = c & 63, ni = (c >> 6) & 1, wd = (c >> 7) & 7, kt = c >> 10;
    const int fr = l & 15, g = l >> 4;
    const int n = wd * 32 + ni * 16 + fr;
    u16 o[8];
#pragma unroll
    for (int j = 0; j < 8; ++j)
      o[j] = f2bf(W2[(kt * 32 + g * 8 + j) * CH2 + n]);
    *(uint4*)(W2s + (size_t)c * 8) = *(const uint4*)o;
  }
}

// ---------------------------------------------------------------- tail copy
__global__ __launch_bounds__(256) void tail_kernel(
    const float* __restrict__ pos_skip, const int* __restrict__ batch_skip,
    float* __restrict__ out) {
  int t = blockIdx.x * 256 + threadIdx.x;   // 262144 total
  if (t < ROWS * 3) {
    out[POS_OUT_OFF + t] = pos_skip[t];
  } else {
    int u = t - ROWS * 3;
    out[BATCH_OUT_OFF + u] = (float)batch_skip[u];
  }
}

// ---------------------------------------------------------------- cell build
__global__ __launch_bounds__(256) void build_kernel(
    const float* __restrict__ pos, float4* __restrict__ pts4,
    u32* __restrict__ cellCnt, int* __restrict__ cellIdx) {
#pragma clang fp contract(off)
  const int i = blockIdx.x * 256 + threadIdx.x;   // 64 blocks -> 16384
  const float x = pos[i * 3 + 0], y = pos[i * 3 + 1], z = pos[i * 3 + 2];
  pts4[i] = make_float4(x, y, z, (x * x + y * y) + z * z);
  const int b = i >> 12;
  int cx = (int)(x * 8.0f); cx = cx < 0 ? 0 : (cx > 7 ? 7 : cx);
  int cy = (int)(y * 8.0f); cy = cy < 0 ? 0 : (cy > 7 ? 7 : cy);
  int cz = (int)(z * 8.0f); cz = cz < 0 ? 0 : (cz > 7 ? 7 : cz);
  const int c = b * 512 + cz * 64 + cy * 8 + cx;
  const u32 slot = atomicAdd(&cellCnt[c], 1u);
  if (slot < CELL_CAP) cellIdx[c * CELL_CAP + slot] = i;
}

// ---------------------------------------------------------------- query bin
__global__ __launch_bounds__(256) void qbin_kernel(
    const float* __restrict__ pos_skip, u32* __restrict__ qCnt,
    int* __restrict__ qIdx) {
  const int q = blockIdx.x * 256 + threadIdx.x;   // 256 blocks -> 65536
  const int b = q >> 14;
  const float qx = pos_skip[q * 3 + 0];
  const float qy = pos_skip[q * 3 + 1];
  const float qz = pos_skip[q * 3 + 2];
  int cx = (int)(qx * 8.0f); cx = cx < 0 ? 0 : (cx > 7 ? 7 : cx);
  int cy = (int)(qy * 8.0f); cy = cy < 0 ? 0 : (cy > 7 ? 7 : cy);
  int cz = (int)(qz * 8.0f); cz = cz < 0 ? 0 : (cz > 7 ? 7 : cz);
  const int c = b * 512 + cz * 64 + cy * 8 + cx;
  const u32 slot = atomicAdd(&qCnt[c], 1u);
  if (slot < QCAP) qIdx[c * QCAP + slot] = q;
}

// ---------------------------------------------------------------- KNN (k=3)
// (validated R7 structure, unchanged)
__global__ __launch_bounds__(256) void knn_kernel(
    const float4* __restrict__ pts4, const u32* __restrict__ cellCnt,
    const int* __restrict__ cellIdx, const u32* __restrict__ qCnt,
    const int* __restrict__ qIdx, const float* __restrict__ pos_skip,
    int* __restrict__ idx_out, float* __restrict__ w_out) {
#pragma clang fp contract(off)
  __shared__ float4 scand[27 * CELL_CAP];
  __shared__ int    scgi[27 * CELL_CAP];
  __shared__ u32    scnt[27];
  __shared__ int    sbase[27];
  __shared__ u32    nCand;
  const int tid = threadIdx.x;
  const int b = blockIdx.x >> 9;
  const int cell = blockIdx.x & 511;
  const int cz = cell >> 6, cy = (cell >> 3) & 7, cx = cell & 7;
  const int x0 = cx > 0 ? cx - 1 : 0, x1 = cx < 7 ? cx + 1 : 7;
  const int y0 = cy > 0 ? cy - 1 : 0, y1 = cy < 7 ? cy + 1 : 7;
  const int z0 = cz > 0 ? cz - 1 : 0, z1 = cz < 7 ? cz + 1 : 7;
  const int nx = x1 - x0 + 1, ny = y1 - y0 + 1, nz = z1 - z0 + 1;
  const int ncells = nx * ny * nz;
  if (tid == 0) nCand = 0;
  if (tid < ncells) {
    const int lz = tid / (nx * ny);
    const int rem = tid - lz * nx * ny;
    const int ly = rem / nx;
    const int lx = rem - ly * nx;
    const int cg = b * 512 + (z0 + lz) * 64 + (y0 + ly) * 8 + (x0 + lx);
    u32 cnt = cellCnt[cg];
    scnt[tid] = cnt > CELL_CAP ? CELL_CAP : cnt;
    sbase[tid] = cg * CELL_CAP;
  }
  __syncthreads();
  const int slots = ncells * CELL_CAP;
  for (int s = tid; s < slots; s += 256) {
    const int ci = s / CELL_CAP;
    const int sl = s - ci * CELL_CAP;
    if ((u32)sl < scnt[ci]) {
      const int gi = cellIdx[sbase[ci] + sl];
      const float4 p = pts4[gi];
      const u32 d = atomicAdd(&nCand, 1u);
      scand[d] = p;
      scgi[d] = gi;
    }
  }
  __syncthreads();
  const int nC = (int)nCand;
  u32 nq = qCnt[b * 512 + cell];
  if (nq > QCAP) nq = QCAP;
  const int qbase = (b * 512 + cell) * QCAP;
  const int g = tid >> 3;
  const int sub = tid & 7;

  for (int r0q = 0; r0q < (int)nq; r0q += 32) {
    const int qslot = r0q + g;
    if (qslot < (int)nq) {
      const int q = qIdx[qbase + qslot];
      const float qx = pos_skip[q * 3 + 0];
      const float qy = pos_skip[q * 3 + 1];
      const float qz = pos_skip[q * 3 + 2];
      const float q2 = (qx * qx + qy * qy) + qz * qz;
      u64 k0 = ~0ull, k1 = ~0ull, k2 = ~0ull;
      for (int s = sub; s < nC; s += 8) {
        const float4 p = scand[s];
        const float dot = fmaf(qz, p.z, fmaf(qy, p.y, qx * p.x));
        const float tv = (q2 - 2.0f * dot) + p.w;
        const u64 key = ((u64)flipf(tv) << 32) | (u32)scgi[s];
        ins3(key, k0, k1, k2);
      }
#pragma unroll
      for (int mask = 1; mask < 8; mask <<= 1) {
        const u64 r0 = shfl_xor_u64_w8(k0, mask);
        const u64 r1 = shfl_xor_u64_w8(k1, mask);
        const u64 r2 = shfl_xor_u64_w8(k2, mask);
        merge3(r0, r1, r2, k0, k1, k2);
      }
      float m2tv = unflipf((u32)(k2 >> 32));
      if (!(m2tv <= 0.015625f - 1e-5f)) {
        k0 = k1 = k2 = ~0ull;
        const int ex0 = cx > 1 ? cx - 2 : 0, ex1 = cx < 6 ? cx + 2 : 7;
        const int ey0 = cy > 1 ? cy - 2 : 0, ey1 = cy < 6 ? cy + 2 : 7;
        const int ez0 = cz > 1 ? cz - 2 : 0, ez1 = cz < 6 ? cz + 2 : 7;
        for (int zz = ez0; zz <= ez1; ++zz)
          for (int yy = ey0; yy <= ey1; ++yy)
            for (int xx = ex0; xx <= ex1; ++xx) {
              const int cg = b * 512 + zz * 64 + yy * 8 + xx;
              u32 cnt = cellCnt[cg];
              if (cnt > CELL_CAP) cnt = CELL_CAP;
              const int cb = cg * CELL_CAP;
              for (int s = sub; s < (int)cnt; s += 8) {
                const int gi = cellIdx[cb + s];
                const float4 p = pts4[gi];
                const float dot = fmaf(qz, p.z, fmaf(qy, p.y, qx * p.x));
                const float tv = (q2 - 2.0f * dot) + p.w;
                ins3(((u64)flipf(tv) << 32) | (u32)gi, k0, k1, k2);
              }
            }
#pragma unroll
        for (int mask = 1; mask < 8; mask <<= 1) {
          const u64 r0 = shfl_xor_u64_w8(k0, mask);
          const u64 r1 = shfl_xor_u64_w8(k1, mask);
          const u64 r2 = shfl_xor_u64_w8(k2, mask);
          merge3(r0, r1, r2, k0, k1, k2);
        }
        m2tv = unflipf((u32)(k2 >> 32));
        if (!(m2tv <= 0.0625f - 1e-5f)) {
          k0 = k1 = k2 = ~0ull;
          const int base = b * NPTS;
          for (int i = sub; i < NPTS; i += 8) {
            const int gi = base + i;
            const float4 p = pts4[gi];
            const float dot = fmaf(qz, p.z, fmaf(qy, p.y, qx * p.x));
            const float tv = (q2 - 2.0f * dot) + p.w;
            ins3(((u64)flipf(tv) << 32) | (u32)gi, k0, k1, k2);
          }
#pragma unroll
          for (int mask = 1; mask < 8; mask <<= 1) {
            const u64 r0 = shfl_xor_u64_w8(k0, mask);
            const u64 r1 = shfl_xor_u64_w8(k1, mask);
            const u64 r2 = shfl_xor_u64_w8(k2, mask);
            merge3(r0, r1, r2, k0, k1, k2);
          }
        }
      }
      if (sub == 0) {
        const float t0 = unflipf((u32)(k0 >> 32));
        const float t1 = unflipf((u32)(k1 >> 32));
        const float t2 = unflipf((u32)(k2 >> 32));
        const float w0 = 1.0f / fmaxf(t0, 1e-16f);
        const float w1 = 1.0f / fmaxf(t1, 1e-16f);
        const float w2 = 1.0f / fmaxf(t2, 1e-16f);
        const float wsum = (w0 + w1) + w2;
        const float inv = 1.0f / wsum;
        idx_out[q * 3 + 0] = (int)(u32)k0;
        idx_out[q * 3 + 1] = (int)(u32)k1;
        idx_out[q * 3 + 2] = (int)(u32)k2;
        w_out[q * 3 + 0] = w0 * inv;
        w_out[q * 3 + 1] = w1 * inv;
        w_out[q * 3 + 2] = w2 * inv;
      }
    }
  }
}

// ---------------------------------------------------------------- fused MLP
// Block = 64 rows, 512 threads. Transposed MFMA phases (A-op = weights,
// B-op = activations): acc[2][4] = 32 AGPR; phase1 in two n32 passes with
// pass-0 held as packed bf16 (16 VGPR). H-writeback = b64 LDS stores;
// final out store = coalesced float4. launch_bounds(512,4) -> <=128 regs
// -> 2 blocks/CU (16 waves/CU).
__global__ __launch_bounds__(512, 4) void fused_mlp_kernel(
    const float* __restrict__ x, const int* __restrict__ idx,
    const float* __restrict__ w, const float* __restrict__ x_skip,
    const u16* __restrict__ W1s, const float* __restrict__ b1,
    const u16* __restrict__ W2s, const float* __restrict__ b2,
    float* __restrict__ out) {
  __shared__ __align__(16) u16 Abuf[64 * 512];   // 64 KB, granule-swizzled
  const int tid = threadIdx.x;
  const int m0 = blockIdx.x * 64;

  // ---- A-build: row = tid>>3 (64 rows), sub = tid&7 (8 x 64-col slices)
  {
    const int row = tid >> 3;
    const int sub = tid & 7;
    const int gr = m0 + row;
    u16* rowp = Abuf + row * 512;
    const int rx = row & 7;
    if (sub < 4) {
      const int i0 = idx[gr * 3 + 0], i1 = idx[gr * 3 + 1], i2 = idx[gr * 3 + 2];
      const float w0 = w[gr * 3 + 0], w1 = w[gr * 3 + 1], w2 = w[gr * 3 + 2];
      const float4* p0 = (const float4*)(x + (size_t)i0 * CIN + sub * 64);
      const float4* p1 = (const float4*)(x + (size_t)i1 * CIN + sub * 64);
      const float4* p2 = (const float4*)(x + (size_t)i2 * CIN + sub * 64);
#pragma unroll
      for (int c = 0; c < 8; ++c) {
        const float4 a0 = p0[c * 2], a1 = p1[c * 2], a2 = p2[c * 2];
        const float4 d0 = p0[c * 2 + 1], d1 = p1[c * 2 + 1], d2 = p2[c * 2 + 1];
        u16 o[8];
        o[0] = f2bf(fmaf(w0, a0.x, fmaf(w1, a1.x, w2 * a2.x)));
        o[1] = f2bf(fmaf(w0, a0.y, fmaf(w1, a1.y, w2 * a2.y)));
        o[2] = f2bf(fmaf(w0, a0.z, fmaf(w1, a1.z, w2 * a2.z)));
        o[3] = f2bf(fmaf(w0, a0.w, fmaf(w1, a1.w, w2 * a2.w)));
        o[4] = f2bf(fmaf(w0, d0.x, fmaf(w1, d1.x, w2 * d2.x)));
        o[5] = f2bf(fmaf(w0, d0.y, fmaf(w1, d1.y, w2 * d2.y)));
        o[6] = f2bf(fmaf(w0, d0.z, fmaf(w1, d1.z, w2 * d2.z)));
        o[7] = f2bf(fmaf(w0, d0.w, fmaf(w1, d1.w, w2 * d2.w)));
        const int vg = sub * 8 + c;
        *(uint4*)(rowp + (vg ^ rx) * 8) = *(const uint4*)o;
      }
    } else {
      const float4* ps = (const float4*)(x_skip + (size_t)gr * CIN + (sub - 4) * 64);
#pragma unroll
      for (int c = 0; c < 8; ++c) {
        const float4 a = ps[c * 2], d = ps[c * 2 + 1];
        u16 o[8];
        o[0] = f2bf(a.x); o[1] = f2bf(a.y); o[2] = f2bf(a.z); o[3] = f2bf(a.w);
        o[4] = f2bf(d.x); o[5] = f2bf(d.y); o[6] = f2bf(d.z); o[7] = f2bf(d.w);
        const int vg = 32 + (sub - 4) * 8 + c;
        *(uint4*)(rowp + (vg ^ rx) * 8) = *(const uint4*)o;
      }
    }
  }
  __syncthreads();

  const int wid = tid >> 6;
  const int lane = tid & 63;
  const int fr = lane & 15;
  const int g = lane >> 4;
  const int frx = fr & 7;

  // ---- phase 1 (transposed, 2 passes): Ht-tile = W1T[n32] x A^T
  f32x4 acc[2][4];
  u32 hold[16];
#pragma unroll
  for (int p = 0; p < 2; ++p) {
#pragma unroll
    for (int mi = 0; mi < 2; mi++)
#pragma unroll
      for (int ni = 0; ni < 4; ni++) acc[mi][ni] = (f32x4){0.f, 0.f, 0.f, 0.f};
    const u16* B1 = W1s + wid * 2048 + (p * 2) * 512 + lane * 8;
    bf16x8 bw[2][2];
#pragma unroll
    for (int i = 0; i < 2; i++) bw[0][i] = *(const bf16x8*)(B1 + i * 512);
    for (int kt = 0; kt < 16; ++kt) {
      const int cur = kt & 1;
      if (kt < 15) {
        const u16* nb = B1 + (kt + 1) * 16384;
#pragma unroll
        for (int i = 0; i < 2; i++)
          bw[cur ^ 1][i] = *(const bf16x8*)(nb + i * 512);
      }
      bf16x8 af[4];
#pragma unroll
      for (int ni = 0; ni < 4; ni++)
        af[ni] = *(const bf16x8*)&Abuf[(ni * 16 + fr) * 512 +
                                       (((kt * 4 + g) ^ frx) * 8)];
#pragma unroll
      for (int mi = 0; mi < 2; mi++)
#pragma unroll
        for (int ni = 0; ni < 4; ni++)
          acc[mi][ni] = __builtin_amdgcn_mfma_f32_16x16x32_bf16(
              bw[cur][mi], af[ni], acc[mi][ni], 0, 0, 0);
    }
    if (p == 0) {
#pragma unroll
      for (int mi = 0; mi < 2; mi++) {
        const int cb = wid * 64 + mi * 16 + g * 4;
        const float4 bv = *(const float4*)&b1[cb];
#pragma unroll
        for (int ni = 0; ni < 4; ni++) {
          const u16 t0 = f2bf(fmaxf(acc[mi][ni][0] + bv.x, 0.f));
          const u16 t1 = f2bf(fmaxf(acc[mi][ni][1] + bv.y, 0.f));
          const u16 t2 = f2bf(fmaxf(acc[mi][ni][2] + bv.z, 0.f));
          const u16 t3 = f2bf(fmaxf(acc[mi][ni][3] + bv.w, 0.f));
          hold[(mi * 4 + ni) * 2 + 0] = (u32)t0 | ((u32)t1 << 16);
          hold[(mi * 4 + ni) * 2 + 1] = (u32)t2 | ((u32)t3 << 16);
        }
      }
    }
  }
  __syncthreads();                 // all Abuf reads (both passes) complete

  // ---- H writeback (b64 LDS stores), H[row][col] same swizzle as Abuf
#pragma unroll
  for (int mi = 0; mi < 2; mi++) {
    {  // pass-0 slice from hold
      const int cb = wid * 64 + mi * 16 + g * 4;
      const int vg = cb >> 3, cl = cb & 7;
#pragma unroll
      for (int ni = 0; ni < 4; ni++) {
        const int row = ni * 16 + fr;
        uint2 pk = make_uint2(hold[(mi * 4 + ni) * 2 + 0],
                              hold[(mi * 4 + ni) * 2 + 1]);
        *(uint2*)&Abuf[row * 512 + (vg ^ (row & 7)) * 8 + cl] = pk;
      }
    }
    {  // pass-1 slice from live acc
      const int cb = wid * 64 + 32 + mi * 16 + g * 4;
      const float4 bv = *(const float4*)&b1[cb];
      const int vg = cb >> 3, cl = cb & 7;
#pragma unroll
      for (int ni = 0; ni < 4; ni++) {
        const int row = ni * 16 + fr;
        uint2 pk;
        pk.x = (u32)f2bf(fmaxf(acc[mi][ni][0] + bv.x, 0.f)) |
               ((u32)f2bf(fmaxf(acc[mi][ni][1] + bv.y, 0.f)) << 16);
        pk.y = (u32)f2bf(fmaxf(acc[mi][ni][2] + bv.z, 0.f)) |
               ((u32)f2bf(fmaxf(acc[mi][ni][3] + bv.w, 0.f)) << 16);
        *(uint2*)&Abuf[row * 512 + (vg ^ (row & 7)) * 8 + cl] = pk;
      }
    }
  }
  __syncthreads();                 // H complete

  // ---- phase 2 (transposed): O-tile = W2T[n32] x H^T
  f32x4 acc2[2][4];
#pragma unroll
  for (int mi = 0; mi < 2; mi++)
#pragma unroll
    for (int ni = 0; ni < 4; ni++) acc2[mi][ni] = (f32x4){0.f, 0.f, 0.f, 0.f};
  {
    const u16* B2 = W2s + wid * 1024 + lane * 8;
    bf16x8 bw[2][2];
#pragma unroll
    for (int i = 0; i < 2; i++) bw[0][i] = *(const bf16x8*)(B2 + i * 512);
    for (int kt = 0; kt < 16; ++kt) {
      const int cur = kt & 1;
      if (kt < 15) {
        const u16* nb = B2 + (kt + 1) * 8192;
#pragma unroll
        for (int i = 0; i < 2; i++)
          bw[cur ^ 1][i] = *(const bf16x8*)(nb + i * 512);
      }
      bf16x8 af[4];
#pragma unroll
      for (int ni = 0; ni < 4; ni++)
        af[ni] = *(const bf16x8*)&Abuf[(ni * 16 + fr) * 512 +
                                       (((kt * 4 + g) ^ frx) * 8)];
#pragma unroll
      for (int mi = 0; mi < 2; mi++)
#pragma unroll
        for (int ni = 0; ni < 4; ni++)
          acc2[mi][ni] = __builtin_amdgcn_mfma_f32_16x16x32_bf16(
              bw[cur][mi], af[ni], acc2[mi][ni], 0, 0, 0);
    }
  }

  // ---- epilogue: relu + bias2 -> coalesced float4 stores
#pragma unroll
  for (int mi = 0; mi < 2; mi++) {
    const int cb = wid * 32 + mi * 16 + g * 4;
    const float4 bv = *(const float4*)&b2[cb];
#pragma unroll
    for (int ni = 0; ni < 4; ni++) {
      const int row = m0 + ni * 16 + fr;
      float4 o;
      o.x = fmaxf(acc2[mi][ni][0] + bv.x, 0.f);
      o.y = fmaxf(acc2[mi][ni][1] + bv.y, 0.f);
      o.z = fmaxf(acc2[mi][ni][2] + bv.z, 0.f);
      o.w = fmaxf(acc2[mi][ni][3] + bv.w, 0.f);
      *(float4*)&out[(size_t)row * CH2 + cb] = o;
    }
  }
}

// ---------------------------------------------------------------- launch
extern "C" void kernel_launch(void* const* d_in, const int* in_sizes, int n_in,
                              void* d_out, int out_size, void* d_ws, size_t ws_size,
                              hipStream_t stream) {
  const float* x        = (const float*)d_in[0];
  const float* pos      = (const float*)d_in[1];
  const float* x_skip   = (const float*)d_in[3];
  const float* pos_skip = (const float*)d_in[4];
  const int*   batch_sk = (const int*)d_in[5];
  const float* W1       = (const float*)d_in[6];
  const float* b1       = (const float*)d_in[7];
  const float* W2       = (const float*)d_in[8];
  const float* b2       = (const float*)d_in[9];
  float* out = (float*)d_out;

  char* ws = (char*)d_ws;
  u16*    W1s     = (u16*)(ws);                 // 524288 B
  u16*    W2s     = (u16*)(ws + 524288);        // 262144 B
  int*    idxb    = (int*)(ws + 786432);        // 786432 B
  float*  wb      = (float*)(ws + 1572864);     // 786432 B
  float4* pts4    = (float4*)(ws + 2359296);    // 262144 B
  u32*    cellCnt = (u32*)(ws + 2621440);       // 8192 B
  u32*    qCnt    = (u32*)(ws + 2629632);       // 8192 B
  int*    cellIdx = (int*)(ws + 2637824);       // 327680 B
  int*    qIdx    = (int*)(ws + 2965504);       // 786432 B

  hipMemsetAsync(cellCnt, 0, 16384, stream);    // cellCnt + qCnt
  prep_kernel<<<dim3(192), dim3(256), 0, stream>>>(W1, W2, W1s, W2s);
  tail_kernel<<<dim3(1024), dim3(256), 0, stream>>>(pos_skip, batch_sk, out);
  build_kernel<<<dim3(64), dim3(256), 0, stream>>>(pos, pts4, cellCnt, cellIdx);
  qbin_kernel<<<dim3(256), dim3(256), 0, stream>>>(pos_skip, qCnt, qIdx);
  knn_kernel<<<dim3(2048), dim3(256), 0, stream>>>(pts4, cellCnt, cellIdx,
                                                   qCnt, qIdx, pos_skip,
                                                   idxb, wb);
  fused_mlp_kernel<<<dim3(1024), dim3(512), 0, stream>>>(
      x, idxb, wb, x_skip, W1s, b1, W2s, b2, out);
}